// Round 3
// baseline (556.230 us; speedup 1.0000x reference)
//
#include <hip/hip_runtime.h>
#include <math.h>

#define NN 512
#define CS 384
#define CZ 128
#define CH 16
#define HH 12
#define PQ 4
#define PV 8

// ---------------- K1: input projections  s @ {Wq, Wkv, Wqp, Wkvp} ----------------
__global__ void k_proj(const float* __restrict__ s,
                       const float* __restrict__ Wq,  const float* __restrict__ bq,
                       const float* __restrict__ Wkv, const float* __restrict__ bkv,
                       const float* __restrict__ Wqp, const float* __restrict__ bqp,
                       const float* __restrict__ Wkvp,const float* __restrict__ bkvp,
                       float* __restrict__ q, float* __restrict__ k, float* __restrict__ v,
                       float* __restrict__ qp_raw, float* __restrict__ kvp_raw)
{
    __shared__ float s_lds[CS];
    int i = blockIdx.x;
    for (int t = threadIdx.x; t < CS; t += blockDim.x)
        s_lds[t] = s[i * CS + t];
    __syncthreads();

    for (int col = threadIdx.x; col < 1152; col += blockDim.x) {
        const float* W; const float* b; int lc, od;
        if (col < 192)      { W = Wq;   b = bq;   lc = col;       od = 192; }
        else if (col < 576) { W = Wkv;  b = bkv;  lc = col - 192; od = 384; }
        else if (col < 720) { W = Wqp;  b = bqp;  lc = col - 576; od = 144; }
        else                { W = Wkvp; b = bkvp; lc = col - 720; od = 432; }
        float acc = b[lc];
        for (int kk = 0; kk < CS; ++kk)
            acc += s_lds[kk] * W[kk * od + lc];

        if (col < 192) {
            q[i * 192 + lc] = acc;
        } else if (col < 576) {
            int h = lc / 32, w = lc % 32;
            if (w < CH) k[(i * HH + h) * CH + w] = acc;
            else        v[(i * HH + h) * CH + (w - CH)] = acc;
        } else if (col < 720) {
            qp_raw[i * 144 + lc] = acc;
        } else {
            kvp_raw[i * 432 + lc] = acc;
        }
    }
}

// ---------------- K2: rotate+translate point projections ----------------
__global__ void k_pts_transform(const float* __restrict__ qp_raw, const float* __restrict__ kvp_raw,
                                const float* __restrict__ rot, const float* __restrict__ trans,
                                float* __restrict__ q_pts, float* __restrict__ k_pts, float* __restrict__ v_pts)
{
    int idx = blockIdx.x * blockDim.x + threadIdx.x;
    const int total = NN * HH * 16;  // 4 q-points + 12 kv-points per (i,h)
    if (idx >= total) return;
    int i = idx / (HH * 16);
    int r = idx % (HH * 16);
    int h = r / 16;
    int p = r % 16;

    float R[9], t3[3];
    for (int a = 0; a < 9; ++a) R[a] = rot[i * 9 + a];
    for (int a = 0; a < 3; ++a) t3[a] = trans[i * 3 + a];

    float x, y, zc;
    if (p < PQ) {
        x  = qp_raw[i * 144 + 0 * 48 + h * PQ + p];
        y  = qp_raw[i * 144 + 1 * 48 + h * PQ + p];
        zc = qp_raw[i * 144 + 2 * 48 + h * PQ + p];
    } else {
        int pp = p - PQ;  // 0..11
        x  = kvp_raw[i * 432 + 0 * 144 + h * 12 + pp];
        y  = kvp_raw[i * 432 + 1 * 144 + h * 12 + pp];
        zc = kvp_raw[i * 432 + 2 * 144 + h * 12 + pp];
    }
    float ox = R[0] * x + R[1] * y + R[2] * zc + t3[0];
    float oy = R[3] * x + R[4] * y + R[5] * zc + t3[1];
    float oz = R[6] * x + R[7] * y + R[8] * zc + t3[2];

    if (p < PQ) {
        int o = ((i * HH + h) * PQ + p) * 3;
        q_pts[o] = ox; q_pts[o + 1] = oy; q_pts[o + 2] = oz;
    } else {
        int pp = p - PQ;
        if (pp < PQ) {
            int o = ((i * HH + h) * PQ + pp) * 3;
            k_pts[o] = ox; k_pts[o + 1] = oy; k_pts[o + 2] = oz;
        } else {
            int o = ((i * HH + h) * PV + (pp - PQ)) * 3;
            v_pts[o] = ox; v_pts[o + 1] = oy; v_pts[o + 2] = oz;
        }
    }
}

// ---------------- K3: attention logits (fused z@Wb bias + qk + point term) ----------------
__global__ void k_logits(const float* __restrict__ z,
                         const float* __restrict__ Wb, const float* __restrict__ bb,
                         const float* __restrict__ q, const float* __restrict__ k,
                         const float* __restrict__ q_pts, const float* __restrict__ k_pts,
                         const float* __restrict__ head_weights,
                         const float* __restrict__ mask,
                         float* __restrict__ logits)
{
    __shared__ float q_lds[HH * CH];       // 192
    __shared__ float qp_lds[HH * PQ * 3];  // 144
    __shared__ float wb_lds[CZ * HH];      // 1536
    __shared__ float hw_lds[HH];

    int i = blockIdx.y;
    int j = blockIdx.x * 256 + threadIdx.x;

    for (int t = threadIdx.x; t < HH * CH; t += 256) q_lds[t] = q[i * HH * CH + t];
    for (int t = threadIdx.x; t < HH * PQ * 3; t += 256) qp_lds[t] = q_pts[i * HH * PQ * 3 + t];
    for (int t = threadIdx.x; t < CZ * HH; t += 256) wb_lds[t] = Wb[t];
    if (threadIdx.x < HH) {
        float x = head_weights[threadIdx.x];
        hw_lds[threadIdx.x] = log1pf(expf(x)) * sqrtf(1.0f / 54.0f);
    }
    __syncthreads();

    float bias[HH];
    for (int h = 0; h < HH; ++h) bias[h] = bb[h];

    const float4* zrow = reinterpret_cast<const float4*>(z + ((size_t)i * NN + j) * CZ);
    for (int cc = 0; cc < CZ / 4; ++cc) {
        float4 pk = zrow[cc];
        int c0 = cc * 4;
        #pragma unroll
        for (int h = 0; h < HH; ++h)
            bias[h] += pk.x * wb_lds[(c0 + 0) * HH + h] + pk.y * wb_lds[(c0 + 1) * HH + h]
                     + pk.z * wb_lds[(c0 + 2) * HH + h] + pk.w * wb_lds[(c0 + 3) * HH + h];
    }

    const float qk_scale = sqrtf(1.0f / 48.0f);
    const float b_scale  = sqrtf(1.0f / 3.0f);

    float lg[HH];
    for (int h = 0; h < HH; ++h) {
        float acc = 0.f;
        const float* kr = k + ((size_t)j * HH + h) * CH;
        #pragma unroll
        for (int c = 0; c < CH; ++c) acc += q_lds[h * CH + c] * kr[c];
        lg[h] = acc * qk_scale + b_scale * bias[h];
    }

    for (int h = 0; h < HH; ++h) {
        float s2 = 0.f;
        #pragma unroll
        for (int p = 0; p < PQ; ++p) {
            const float* kp = k_pts + (((size_t)j * HH + h) * PQ + p) * 3;
            float dx = qp_lds[(h * PQ + p) * 3 + 0] - kp[0];
            float dy = qp_lds[(h * PQ + p) * 3 + 1] - kp[1];
            float dz = qp_lds[(h * PQ + p) * 3 + 2] - kp[2];
            s2 += dx * dx + dy * dy + dz * dz;
        }
        lg[h] -= 0.5f * hw_lds[h] * s2;
    }

    float mi = mask[i], mj = mask[j];
    float sqm = 100000.0f * (mi * mj - 1.0f);
    for (int h = 0; h < HH; ++h)
        logits[((size_t)h * NN + i) * NN + j] = lg[h] + sqm;
}

// ---------------- K4: row softmax (one wave per (h,i) row) ----------------
__global__ void k_softmax(float* __restrict__ logits)
{
    int row = blockIdx.x;  // h*NN + i
    float* p = logits + (size_t)row * NN;
    int t = threadIdx.x;
    float vals[8];
    float m = -1e30f;
    #pragma unroll
    for (int u = 0; u < 8; ++u) { vals[u] = p[t + u * 64]; m = fmaxf(m, vals[u]); }
    #pragma unroll
    for (int off = 32; off >= 1; off >>= 1) m = fmaxf(m, __shfl_xor(m, off));
    float ssum = 0.f;
    #pragma unroll
    for (int u = 0; u < 8; ++u) { vals[u] = expf(vals[u] - m); ssum += vals[u]; }
    #pragma unroll
    for (int off = 32; off >= 1; off >>= 1) ssum += __shfl_xor(ssum, off);
    float inv = 1.0f / ssum;
    #pragma unroll
    for (int u = 0; u < 8; ++u) p[t + u * 64] = vals[u] * inv;
}

// ---------------- K5: o = a·v and o_pt = a·v_pts (+ inverse frame, norms) ----------------
__global__ void k_out_ov(const float* __restrict__ logits, const float* __restrict__ v,
                         const float* __restrict__ v_pts,
                         const float* __restrict__ rot, const float* __restrict__ trans,
                         float* __restrict__ cat)
{
    __shared__ float a_lds[HH][NN];        // 24 KB
    __shared__ float opt_lds[HH * PV * 3]; // 288 floats
    int i = blockIdx.x;
    for (int h = 0; h < HH; ++h)
        for (int j = threadIdx.x; j < NN; j += 256)
            a_lds[h][j] = logits[((size_t)h * NN + i) * NN + j];
    __syncthreads();

    for (int out = threadIdx.x; out < 480; out += 256) {
        float acc = 0.f;
        if (out < 192) {
            int h = out / CH;
            for (int j = 0; j < NN; ++j)
                acc += a_lds[h][j] * v[(size_t)j * 192 + out];
            cat[(size_t)i * 2112 + out] = acc;
        } else {
            int r = out - 192;       // (h*PV+p)*3 + d
            int h = r / (PV * 3);
            for (int j = 0; j < NN; ++j)
                acc += a_lds[h][j] * v_pts[(size_t)j * (HH * PV * 3) + r];
            opt_lds[r] = acc;
        }
    }
    __syncthreads();

    if (threadIdx.x < HH * PV) {
        int hp = threadIdx.x;
        float R[9], t3[3];
        for (int a = 0; a < 9; ++a) R[a] = rot[i * 9 + a];
        for (int a = 0; a < 3; ++a) t3[a] = trans[i * 3 + a];
        float gx = opt_lds[hp * 3 + 0] - t3[0];
        float gy = opt_lds[hp * 3 + 1] - t3[1];
        float gz = opt_lds[hp * 3 + 2] - t3[2];
        // local = R^T * g
        float lx = R[0] * gx + R[3] * gy + R[6] * gz;
        float ly = R[1] * gx + R[4] * gy + R[7] * gz;
        float lz = R[2] * gx + R[5] * gy + R[8] * gz;
        float* crow = cat + (size_t)i * 2112;
        crow[192 + 0 * 96 + hp] = lx;
        crow[192 + 1 * 96 + hp] = ly;
        crow[192 + 2 * 96 + hp] = lz;
        crow[480 + hp] = sqrtf(lx * lx + ly * ly + lz * lz + 1e-8f);
    }
}

// ---------------- K6: o_pair = a · z ----------------
__global__ void k_out_pair(const float* __restrict__ logits, const float* __restrict__ z,
                           float* __restrict__ cat)
{
    __shared__ float a_lds[NN][HH];      // j-major, 24 KB
    __shared__ float part[2][CZ][HH];    // 12 KB
    int i = blockIdx.x;
    for (int h = 0; h < HH; ++h)
        for (int j = threadIdx.x; j < NN; j += 256)
            a_lds[j][h] = logits[((size_t)h * NN + i) * NN + j];
    __syncthreads();

    int c = threadIdx.x & 127;
    int half = threadIdx.x >> 7;
    float acc[HH];
    #pragma unroll
    for (int h = 0; h < HH; ++h) acc[h] = 0.f;

    const float* zbase = z + ((size_t)i * NN) * CZ + c;
    int j0 = half * 256;
    for (int j = j0; j < j0 + 256; ++j) {
        float zv = zbase[(size_t)j * CZ];
        #pragma unroll
        for (int h = 0; h < HH; ++h) acc[h] += a_lds[j][h] * zv;
    }
    #pragma unroll
    for (int h = 0; h < HH; ++h) part[half][c][h] = acc[h];
    __syncthreads();

    if (threadIdx.x < CZ) {
        float* crow = cat + (size_t)i * 2112 + 576;
        for (int h = 0; h < HH; ++h)
            crow[h * CZ + threadIdx.x] = part[0][threadIdx.x][h] + part[1][threadIdx.x][h];
    }
}

// ---------------- K7: out = cat @ Wout + bout  (fp32 output) ----------------
__global__ void k_final(const float* __restrict__ cat, const float* __restrict__ Wout,
                        const float* __restrict__ bout, float* __restrict__ out)
{
    __shared__ float c_lds[4][2112];  // 33 KB
    int i0 = blockIdx.x * 4;
    for (int r = 0; r < 4; ++r)
        for (int t = threadIdx.x; t < 2112; t += 384)
            c_lds[r][t] = cat[(size_t)(i0 + r) * 2112 + t];
    __syncthreads();

    int col = threadIdx.x;  // 384 threads
    float acc[4];
    float b = bout[col];
    #pragma unroll
    for (int r = 0; r < 4; ++r) acc[r] = b;
    for (int kk = 0; kk < 2112; ++kk) {
        float w = Wout[(size_t)kk * 384 + col];
        #pragma unroll
        for (int r = 0; r < 4; ++r) acc[r] += c_lds[r][kk] * w;
    }
    #pragma unroll
    for (int r = 0; r < 4; ++r)
        out[(size_t)(i0 + r) * 384 + col] = acc[r];
}

extern "C" void kernel_launch(void* const* d_in, const int* in_sizes, int n_in,
                              void* d_out, int out_size, void* d_ws, size_t ws_size,
                              hipStream_t stream)
{
    const float* s     = (const float*)d_in[0];
    const float* z     = (const float*)d_in[1];
    const float* rot   = (const float*)d_in[2];
    const float* trans = (const float*)d_in[3];
    const float* mask  = (const float*)d_in[4];
    const float* Wq    = (const float*)d_in[5];
    const float* bq    = (const float*)d_in[6];
    const float* Wkv   = (const float*)d_in[7];
    const float* bkv   = (const float*)d_in[8];
    const float* Wqp   = (const float*)d_in[9];
    const float* bqp   = (const float*)d_in[10];
    const float* Wkvp  = (const float*)d_in[11];
    const float* bkvp  = (const float*)d_in[12];
    const float* Wb    = (const float*)d_in[13];
    const float* bb    = (const float*)d_in[14];
    const float* hw    = (const float*)d_in[15];
    const float* Wout  = (const float*)d_in[16];
    const float* bout  = (const float*)d_in[17];
    float* out = (float*)d_out;

    float* ws = (float*)d_ws;
    float* q       = ws;            // 98304
    float* k       = ws + 98304;    // 98304
    float* v       = ws + 196608;   // 98304
    float* qp_raw  = ws + 294912;   // 73728
    float* kvp_raw = ws + 368640;   // 221184
    float* q_pts   = ws + 589824;   // 73728
    float* k_pts   = ws + 663552;   // 73728
    float* v_pts   = ws + 737280;   // 147456
    float* logits  = ws + 884736;   // 3145728
    float* cat     = ws + 4030464;  // 1081344  (total 5111808 floats = 20.5 MB)

    hipLaunchKernelGGL(k_proj, dim3(NN), dim3(256), 0, stream,
                       s, Wq, bq, Wkv, bkv, Wqp, bqp, Wkvp, bkvp, q, k, v, qp_raw, kvp_raw);
    hipLaunchKernelGGL(k_pts_transform, dim3(384), dim3(256), 0, stream,
                       qp_raw, kvp_raw, rot, trans, q_pts, k_pts, v_pts);
    hipLaunchKernelGGL(k_logits, dim3(2, NN), dim3(256), 0, stream,
                       z, Wb, bb, q, k, q_pts, k_pts, hw, mask, logits);
    hipLaunchKernelGGL(k_softmax, dim3(HH * NN), dim3(64), 0, stream, logits);
    hipLaunchKernelGGL(k_out_ov, dim3(NN), dim3(256), 0, stream,
                       logits, v, v_pts, rot, trans, cat);
    hipLaunchKernelGGL(k_out_pair, dim3(NN), dim3(256), 0, stream, logits, z, cat);
    hipLaunchKernelGGL(k_final, dim3(NN / 4), dim3(384), 0, stream, cat, Wout, bout, out);
}

// Round 4
// 474.665 us; speedup vs baseline: 1.1718x; 1.1718x over previous
//
#include <hip/hip_runtime.h>
#include <math.h>

#define NN 512
#define CS 384
#define CZ 128
#define CH 16
#define HH 12
#define PQ 4
#define PV 8

typedef float f32x4 __attribute__((ext_vector_type(4)));
typedef __bf16 bf16x8 __attribute__((ext_vector_type(8)));

// ---------------- K1: input projections  s @ {Wq, Wkv, Wqp, Wkvp} ----------------
__global__ void k_proj(const float* __restrict__ s,
                       const float* __restrict__ Wq,  const float* __restrict__ bq,
                       const float* __restrict__ Wkv, const float* __restrict__ bkv,
                       const float* __restrict__ Wqp, const float* __restrict__ bqp,
                       const float* __restrict__ Wkvp,const float* __restrict__ bkvp,
                       float* __restrict__ q, float* __restrict__ k, float* __restrict__ v,
                       float* __restrict__ qp_raw, float* __restrict__ kvp_raw)
{
    __shared__ float s_lds[CS];
    int i = blockIdx.x;
    for (int t = threadIdx.x; t < CS; t += blockDim.x)
        s_lds[t] = s[i * CS + t];
    __syncthreads();

    for (int col = threadIdx.x; col < 1152; col += blockDim.x) {
        const float* W; const float* b; int lc, od;
        if (col < 192)      { W = Wq;   b = bq;   lc = col;       od = 192; }
        else if (col < 576) { W = Wkv;  b = bkv;  lc = col - 192; od = 384; }
        else if (col < 720) { W = Wqp;  b = bqp;  lc = col - 576; od = 144; }
        else                { W = Wkvp; b = bkvp; lc = col - 720; od = 432; }
        float acc = b[lc];
        for (int kk = 0; kk < CS; ++kk)
            acc += s_lds[kk] * W[kk * od + lc];

        if (col < 192) {
            q[i * 192 + lc] = acc;
        } else if (col < 576) {
            int h = lc / 32, w = lc % 32;
            if (w < CH) k[(i * HH + h) * CH + w] = acc;
            else        v[(i * HH + h) * CH + (w - CH)] = acc;
        } else if (col < 720) {
            qp_raw[i * 144 + lc] = acc;
        } else {
            kvp_raw[i * 432 + lc] = acc;
        }
    }
}

// ---------------- K2: rotate+translate point projections ----------------
__global__ void k_pts_transform(const float* __restrict__ qp_raw, const float* __restrict__ kvp_raw,
                                const float* __restrict__ rot, const float* __restrict__ trans,
                                float* __restrict__ q_pts, float* __restrict__ k_pts, float* __restrict__ v_pts)
{
    int idx = blockIdx.x * blockDim.x + threadIdx.x;
    const int total = NN * HH * 16;
    if (idx >= total) return;
    int i = idx / (HH * 16);
    int r = idx % (HH * 16);
    int h = r / 16;
    int p = r % 16;

    float R[9], t3[3];
    for (int a = 0; a < 9; ++a) R[a] = rot[i * 9 + a];
    for (int a = 0; a < 3; ++a) t3[a] = trans[i * 3 + a];

    float x, y, zc;
    if (p < PQ) {
        x  = qp_raw[i * 144 + 0 * 48 + h * PQ + p];
        y  = qp_raw[i * 144 + 1 * 48 + h * PQ + p];
        zc = qp_raw[i * 144 + 2 * 48 + h * PQ + p];
    } else {
        int pp = p - PQ;
        x  = kvp_raw[i * 432 + 0 * 144 + h * 12 + pp];
        y  = kvp_raw[i * 432 + 1 * 144 + h * 12 + pp];
        zc = kvp_raw[i * 432 + 2 * 144 + h * 12 + pp];
    }
    float ox = R[0] * x + R[1] * y + R[2] * zc + t3[0];
    float oy = R[3] * x + R[4] * y + R[5] * zc + t3[1];
    float oz = R[6] * x + R[7] * y + R[8] * zc + t3[2];

    if (p < PQ) {
        int o = ((i * HH + h) * PQ + p) * 3;
        q_pts[o] = ox; q_pts[o + 1] = oy; q_pts[o + 2] = oz;
    } else {
        int pp = p - PQ;
        if (pp < PQ) {
            int o = ((i * HH + h) * PQ + pp) * 3;
            k_pts[o] = ox; k_pts[o + 1] = oy; k_pts[o + 2] = oz;
        } else {
            int o = ((i * HH + h) * PV + (pp - PQ)) * 3;
            v_pts[o] = ox; v_pts[o + 1] = oy; v_pts[o + 2] = oz;
        }
    }
}

// ---------------- K2b: bias GEMM  b_bias[h,i,j] = (z @ Wb)  via bf16 MFMA ----------------
// M = (i,j) rows, N = 12 heads (padded to 16), K = 128.
// A-frag: A[m=lane&15][k=quad*8+jj]; B-frag: B[k=quad*8+jj][n=lane&15];
// C/D: col=lane&15, row=quad*4+reg   (gfx950-verified layouts)
__global__ void k_bias(const float* __restrict__ z, const float* __restrict__ Wb,
                       float* __restrict__ b_bias)
{
    int i = blockIdx.x;
    int lane = threadIdx.x & 63;
    int wave = threadIdx.x >> 6;   // 0..3
    int col  = lane & 15;
    int quad = lane >> 4;

    bf16x8 bfrag[4];
    #pragma unroll
    for (int kc = 0; kc < 4; ++kc) {
        #pragma unroll
        for (int jj = 0; jj < 8; ++jj) {
            int c = kc * 32 + quad * 8 + jj;
            float wv = (col < HH) ? Wb[c * HH + col] : 0.0f;
            bfrag[kc][jj] = (__bf16)wv;
        }
    }

    for (int tt = 0; tt < 8; ++tt) {
        int j0 = (wave + 4 * tt) * 16;
        const float* zrow = z + ((size_t)i * NN + j0 + col) * CZ;
        f32x4 acc = {0.f, 0.f, 0.f, 0.f};
        #pragma unroll
        for (int kc = 0; kc < 4; ++kc) {
            float4 z0 = *(const float4*)(zrow + kc * 32 + quad * 8);
            float4 z1 = *(const float4*)(zrow + kc * 32 + quad * 8 + 4);
            bf16x8 afrag;
            afrag[0] = (__bf16)z0.x; afrag[1] = (__bf16)z0.y;
            afrag[2] = (__bf16)z0.z; afrag[3] = (__bf16)z0.w;
            afrag[4] = (__bf16)z1.x; afrag[5] = (__bf16)z1.y;
            afrag[6] = (__bf16)z1.z; afrag[7] = (__bf16)z1.w;
            acc = __builtin_amdgcn_mfma_f32_16x16x32_bf16(afrag, bfrag[kc], acc, 0, 0, 0);
        }
        if (col < HH) {
            #pragma unroll
            for (int r = 0; r < 4; ++r) {
                int j = j0 + quad * 4 + r;
                b_bias[((size_t)col * NN + i) * NN + j] = acc[r];
            }
        }
    }
}

// ---------------- K3: attention logits (bias precomputed; no z here) ----------------
__global__ void k_logits(const float* __restrict__ b_bias, const float* __restrict__ bb,
                         const float* __restrict__ q, const float* __restrict__ k,
                         const float* __restrict__ q_pts, const float* __restrict__ k_pts,
                         const float* __restrict__ head_weights,
                         const float* __restrict__ mask,
                         float* __restrict__ logits)
{
    __shared__ float q_lds[HH * CH];
    __shared__ float qp_lds[HH * PQ * 3];
    __shared__ float hw_lds[HH];

    int i = blockIdx.y;
    int j = blockIdx.x * 256 + threadIdx.x;

    for (int t = threadIdx.x; t < HH * CH; t += 256) q_lds[t] = q[i * HH * CH + t];
    for (int t = threadIdx.x; t < HH * PQ * 3; t += 256) qp_lds[t] = q_pts[i * HH * PQ * 3 + t];
    if (threadIdx.x < HH) {
        float x = head_weights[threadIdx.x];
        hw_lds[threadIdx.x] = log1pf(expf(x)) * sqrtf(1.0f / 54.0f);
    }
    __syncthreads();

    const float qk_scale = sqrtf(1.0f / 48.0f);
    const float b_scale  = sqrtf(1.0f / 3.0f);

    float lg[HH];
    #pragma unroll
    for (int h = 0; h < HH; ++h) {
        float bias_h = b_bias[((size_t)h * NN + i) * NN + j] + bb[h];
        float acc = 0.f;
        const float* kr = k + ((size_t)j * HH + h) * CH;
        #pragma unroll
        for (int c = 0; c < CH; ++c) acc += q_lds[h * CH + c] * kr[c];
        lg[h] = acc * qk_scale + b_scale * bias_h;
    }

    #pragma unroll
    for (int h = 0; h < HH; ++h) {
        float s2 = 0.f;
        #pragma unroll
        for (int p = 0; p < PQ; ++p) {
            const float* kp = k_pts + (((size_t)j * HH + h) * PQ + p) * 3;
            float dx = qp_lds[(h * PQ + p) * 3 + 0] - kp[0];
            float dy = qp_lds[(h * PQ + p) * 3 + 1] - kp[1];
            float dz = qp_lds[(h * PQ + p) * 3 + 2] - kp[2];
            s2 += dx * dx + dy * dy + dz * dz;
        }
        lg[h] -= 0.5f * hw_lds[h] * s2;
    }

    float mi = mask[i], mj = mask[j];
    float sqm = 100000.0f * (mi * mj - 1.0f);
    #pragma unroll
    for (int h = 0; h < HH; ++h)
        logits[((size_t)h * NN + i) * NN + j] = lg[h] + sqm;
}

// ---------------- K4: row softmax ----------------
__global__ void k_softmax(float* __restrict__ logits)
{
    int row = blockIdx.x;
    float* p = logits + (size_t)row * NN;
    int t = threadIdx.x;
    float vals[8];
    float m = -1e30f;
    #pragma unroll
    for (int u = 0; u < 8; ++u) { vals[u] = p[t + u * 64]; m = fmaxf(m, vals[u]); }
    #pragma unroll
    for (int off = 32; off >= 1; off >>= 1) m = fmaxf(m, __shfl_xor(m, off));
    float ssum = 0.f;
    #pragma unroll
    for (int u = 0; u < 8; ++u) { vals[u] = expf(vals[u] - m); ssum += vals[u]; }
    #pragma unroll
    for (int off = 32; off >= 1; off >>= 1) ssum += __shfl_xor(ssum, off);
    float inv = 1.0f / ssum;
    #pragma unroll
    for (int u = 0; u < 8; ++u) p[t + u * 64] = vals[u] * inv;
}

// ---------------- K5: o = a·v and o_pt = a·v_pts (+ inverse frame, norms) ----------------
__global__ void k_out_ov(const float* __restrict__ logits, const float* __restrict__ v,
                         const float* __restrict__ v_pts,
                         const float* __restrict__ rot, const float* __restrict__ trans,
                         float* __restrict__ cat)
{
    __shared__ float a_lds[HH][NN];
    __shared__ float opt_lds[HH * PV * 3];
    int i = blockIdx.x;
    for (int h = 0; h < HH; ++h)
        for (int j = threadIdx.x; j < NN; j += 256)
            a_lds[h][j] = logits[((size_t)h * NN + i) * NN + j];
    __syncthreads();

    for (int out = threadIdx.x; out < 480; out += 256) {
        float acc = 0.f;
        if (out < 192) {
            int h = out / CH;
            for (int j = 0; j < NN; ++j)
                acc += a_lds[h][j] * v[(size_t)j * 192 + out];
            cat[(size_t)i * 2112 + out] = acc;
        } else {
            int r = out - 192;
            int h = r / (PV * 3);
            for (int j = 0; j < NN; ++j)
                acc += a_lds[h][j] * v_pts[(size_t)j * (HH * PV * 3) + r];
            opt_lds[r] = acc;
        }
    }
    __syncthreads();

    if (threadIdx.x < HH * PV) {
        int hp = threadIdx.x;
        float R[9], t3[3];
        for (int a = 0; a < 9; ++a) R[a] = rot[i * 9 + a];
        for (int a = 0; a < 3; ++a) t3[a] = trans[i * 3 + a];
        float gx = opt_lds[hp * 3 + 0] - t3[0];
        float gy = opt_lds[hp * 3 + 1] - t3[1];
        float gz = opt_lds[hp * 3 + 2] - t3[2];
        float lx = R[0] * gx + R[3] * gy + R[6] * gz;
        float ly = R[1] * gx + R[4] * gy + R[7] * gz;
        float lz = R[2] * gx + R[5] * gy + R[8] * gz;
        float* crow = cat + (size_t)i * 2112;
        crow[192 + 0 * 96 + hp] = lx;
        crow[192 + 1 * 96 + hp] = ly;
        crow[192 + 2 * 96 + hp] = lz;
        crow[480 + hp] = sqrtf(lx * lx + ly * ly + lz * lz + 1e-8f);
    }
}

// ---------------- K6: o_pair = a · z ----------------
__global__ void k_out_pair(const float* __restrict__ logits, const float* __restrict__ z,
                           float* __restrict__ cat)
{
    __shared__ float a_lds[NN][HH];
    __shared__ float part[2][CZ][HH];
    int i = blockIdx.x;
    for (int h = 0; h < HH; ++h)
        for (int j = threadIdx.x; j < NN; j += 256)
            a_lds[j][h] = logits[((size_t)h * NN + i) * NN + j];
    __syncthreads();

    int c = threadIdx.x & 127;
    int half = threadIdx.x >> 7;
    float acc[HH];
    #pragma unroll
    for (int h = 0; h < HH; ++h) acc[h] = 0.f;

    const float* zbase = z + ((size_t)i * NN) * CZ + c;
    int j0 = half * 256;
    for (int j = j0; j < j0 + 256; ++j) {
        float zv = zbase[(size_t)j * CZ];
        #pragma unroll
        for (int h = 0; h < HH; ++h) acc[h] += a_lds[j][h] * zv;
    }
    #pragma unroll
    for (int h = 0; h < HH; ++h) part[half][c][h] = acc[h];
    __syncthreads();

    if (threadIdx.x < CZ) {
        float* crow = cat + (size_t)i * 2112 + 576;
        for (int h = 0; h < HH; ++h)
            crow[h * CZ + threadIdx.x] = part[0][threadIdx.x][h] + part[1][threadIdx.x][h];
    }
}

// ---------------- K7: out = cat @ Wout + bout — tiled split-K GEMM ----------------
// grid (6 n-tiles, 8 m-tiles, 4 k-splits), 256 threads; 64x64 tile, Kc=48, 11 stages.
__global__ void k_final(const float* __restrict__ cat, const float* __restrict__ Wout,
                        const float* __restrict__ bout, float* __restrict__ out)
{
    __shared__ float As[64 * 52];  // [m][k], k-dim padded 48->52
    __shared__ float Bs[48 * 64];  // [k][n]

    int tx = threadIdx.x & 15;     // n quadrant
    int ty = threadIdx.x >> 4;     // m quadrant
    int n0 = blockIdx.x * 64;
    int m0 = blockIdx.y * 64;
    int k0 = blockIdx.z * 528;

    float acc[4][4];
    #pragma unroll
    for (int r = 0; r < 4; ++r)
        #pragma unroll
        for (int cc = 0; cc < 4; ++cc) acc[r][cc] = 0.f;

    for (int stage = 0; stage < 11; ++stage) {
        int kb = k0 + stage * 48;
        #pragma unroll
        for (int e = 0; e < 12; ++e) {
            int idx = e * 256 + threadIdx.x;       // 0..3071
            int m = idx / 48, kk = idx % 48;
            As[m * 52 + kk] = cat[(size_t)(m0 + m) * 2112 + kb + kk];
        }
        #pragma unroll
        for (int e = 0; e < 12; ++e) {
            int idx = e * 256 + threadIdx.x;
            int kk = idx >> 6, n = idx & 63;
            Bs[kk * 64 + n] = Wout[(size_t)(kb + kk) * 384 + n0 + n];
        }
        __syncthreads();

        for (int kk = 0; kk < 48; kk += 4) {
            f32x4 a[4], b[4];
            #pragma unroll
            for (int r = 0; r < 4; ++r)
                a[r] = *(const f32x4*)&As[(ty * 4 + r) * 52 + kk];
            #pragma unroll
            for (int kq = 0; kq < 4; ++kq)
                b[kq] = *(const f32x4*)&Bs[(kk + kq) * 64 + tx * 4];
            #pragma unroll
            for (int kq = 0; kq < 4; ++kq)
                #pragma unroll
                for (int r = 0; r < 4; ++r)
                    #pragma unroll
                    for (int cc = 0; cc < 4; ++cc)
                        acc[r][cc] += a[r][kq] * b[kq][cc];
        }
        __syncthreads();
    }

    bool add_bias = (blockIdx.z == 0);
    #pragma unroll
    for (int r = 0; r < 4; ++r) {
        int m = m0 + ty * 4 + r;
        #pragma unroll
        for (int cc = 0; cc < 4; ++cc) {
            int n = n0 + tx * 4 + cc;
            float val = acc[r][cc] + (add_bias ? bout[n] : 0.f);
            atomicAdd(&out[(size_t)m * 384 + n], val);
        }
    }
}

extern "C" void kernel_launch(void* const* d_in, const int* in_sizes, int n_in,
                              void* d_out, int out_size, void* d_ws, size_t ws_size,
                              hipStream_t stream)
{
    const float* s     = (const float*)d_in[0];
    const float* z     = (const float*)d_in[1];
    const float* rot   = (const float*)d_in[2];
    const float* trans = (const float*)d_in[3];
    const float* mask  = (const float*)d_in[4];
    const float* Wq    = (const float*)d_in[5];
    const float* bq    = (const float*)d_in[6];
    const float* Wkv   = (const float*)d_in[7];
    const float* bkv   = (const float*)d_in[8];
    const float* Wqp   = (const float*)d_in[9];
    const float* bqp   = (const float*)d_in[10];
    const float* Wkvp  = (const float*)d_in[11];
    const float* bkvp  = (const float*)d_in[12];
    const float* Wb    = (const float*)d_in[13];
    const float* bb    = (const float*)d_in[14];
    const float* hw    = (const float*)d_in[15];
    const float* Wout  = (const float*)d_in[16];
    const float* bout  = (const float*)d_in[17];
    float* out = (float*)d_out;

    float* ws = (float*)d_ws;
    float* q       = ws;            // 98304
    float* k       = ws + 98304;    // 98304
    float* v       = ws + 196608;   // 98304
    float* qp_raw  = ws + 294912;   // 73728
    float* kvp_raw = ws + 368640;   // 221184
    float* q_pts   = ws + 589824;   // 73728
    float* k_pts   = ws + 663552;   // 73728
    float* v_pts   = ws + 737280;   // 147456
    float* logits  = ws + 884736;   // 3145728
    float* b_bias  = ws + 4030464;  // 3145728 (12.6 MB; dead after k_logits)
    float* cat     = ws + 7176192;  // 1081344  (total ~33 MB)

    hipMemsetAsync(out, 0, (size_t)NN * CS * sizeof(float), stream);

    hipLaunchKernelGGL(k_proj, dim3(NN), dim3(256), 0, stream,
                       s, Wq, bq, Wkv, bkv, Wqp, bqp, Wkvp, bkvp, q, k, v, qp_raw, kvp_raw);
    hipLaunchKernelGGL(k_pts_transform, dim3(384), dim3(256), 0, stream,
                       qp_raw, kvp_raw, rot, trans, q_pts, k_pts, v_pts);
    hipLaunchKernelGGL(k_bias, dim3(NN), dim3(256), 0, stream, z, Wb, b_bias);
    hipLaunchKernelGGL(k_logits, dim3(2, NN), dim3(256), 0, stream,
                       b_bias, bb, q, k, q_pts, k_pts, hw, mask, logits);
    hipLaunchKernelGGL(k_softmax, dim3(HH * NN), dim3(64), 0, stream, logits);
    hipLaunchKernelGGL(k_out_ov, dim3(NN), dim3(256), 0, stream,
                       logits, v, v_pts, rot, trans, cat);
    hipLaunchKernelGGL(k_out_pair, dim3(NN), dim3(256), 0, stream, logits, z, cat);
    hipLaunchKernelGGL(k_final, dim3(6, 8, 4), dim3(256), 0, stream, cat, Wout, bout, out);
}

// Round 5
// 434.154 us; speedup vs baseline: 1.2812x; 1.0933x over previous
//
#include <hip/hip_runtime.h>
#include <math.h>

#define NN 512
#define CS 384
#define CZ 128
#define CH 16
#define HH 12
#define PQ 4
#define PV 8

typedef float f32x4 __attribute__((ext_vector_type(4)));
typedef __bf16 bf16x8 __attribute__((ext_vector_type(8)));

// ---------------- K0: repack weights into Wcat[384][1152] + bcat[1152] ----------------
__global__ void k_repack(const float* __restrict__ Wq,  const float* __restrict__ bq,
                         const float* __restrict__ Wkv, const float* __restrict__ bkv,
                         const float* __restrict__ Wqp, const float* __restrict__ bqp,
                         const float* __restrict__ Wkvp,const float* __restrict__ bkvp,
                         float* __restrict__ Wcat, float* __restrict__ bcat)
{
    const int total = CS * 1152;
    for (int idx = blockIdx.x * blockDim.x + threadIdx.x; idx < total; idx += gridDim.x * blockDim.x) {
        int kk = idx / 1152, n = idx % 1152;
        float vv;
        if (n < 192)      vv = Wq  [kk * 192 + n];
        else if (n < 576) vv = Wkv [kk * 384 + (n - 192)];
        else if (n < 720) vv = Wqp [kk * 144 + (n - 576)];
        else              vv = Wkvp[kk * 432 + (n - 720)];
        Wcat[idx] = vv;
    }
    int n = blockIdx.x * blockDim.x + threadIdx.x;
    if (n < 1152) {
        float vv;
        if (n < 192)      vv = bq  [n];
        else if (n < 576) vv = bkv [n - 192];
        else if (n < 720) vv = bqp [n - 576];
        else              vv = bkvp[n - 720];
        bcat[n] = vv;
    }
}

// ---------------- K1: s @ Wcat — tiled GEMM, 64x64 tile, 4x4 microtile ----------------
__global__ void k_proj(const float* __restrict__ s, const float* __restrict__ Wcat,
                       const float* __restrict__ bcat,
                       float* __restrict__ q, float* __restrict__ k, float* __restrict__ v,
                       float* __restrict__ qp_raw, float* __restrict__ kvp_raw)
{
    __shared__ float As[64 * 68];  // [m][k], stride 68
    __shared__ float Bs[64 * 64];  // [k][n]

    int tx = threadIdx.x & 15;
    int ty = threadIdx.x >> 4;
    int n0 = blockIdx.x * 64;
    int m0 = blockIdx.y * 64;

    float acc[4][4];
    #pragma unroll
    for (int r = 0; r < 4; ++r)
        #pragma unroll
        for (int cc = 0; cc < 4; ++cc) acc[r][cc] = 0.f;

    for (int kb = 0; kb < CS; kb += 64) {
        #pragma unroll
        for (int e = 0; e < 16; ++e) {
            int idx = e * 256 + threadIdx.x;
            int m = idx >> 6, kk = idx & 63;
            As[m * 68 + kk] = s[(size_t)(m0 + m) * CS + kb + kk];
        }
        #pragma unroll
        for (int e = 0; e < 16; ++e) {
            int idx = e * 256 + threadIdx.x;
            int kk = idx >> 6, n = idx & 63;
            Bs[kk * 64 + n] = Wcat[(size_t)(kb + kk) * 1152 + n0 + n];
        }
        __syncthreads();

        for (int kk = 0; kk < 64; kk += 4) {
            f32x4 a[4], b[4];
            #pragma unroll
            for (int r = 0; r < 4; ++r)
                a[r] = *(const f32x4*)&As[(ty * 4 + r) * 68 + kk];
            #pragma unroll
            for (int kq = 0; kq < 4; ++kq)
                b[kq] = *(const f32x4*)&Bs[(kk + kq) * 64 + tx * 4];
            #pragma unroll
            for (int kq = 0; kq < 4; ++kq)
                #pragma unroll
                for (int r = 0; r < 4; ++r)
                    #pragma unroll
                    for (int cc = 0; cc < 4; ++cc)
                        acc[r][cc] += a[r][kq] * b[kq][cc];
        }
        __syncthreads();
    }

    #pragma unroll
    for (int r = 0; r < 4; ++r) {
        int i = m0 + ty * 4 + r;
        #pragma unroll
        for (int cc = 0; cc < 4; ++cc) {
            int col = n0 + tx * 4 + cc;
            float val = acc[r][cc] + bcat[col];
            if (col < 192) {
                q[i * 192 + col] = val;
            } else if (col < 576) {
                int lc = col - 192;
                int h = lc / 32, w = lc % 32;
                if (w < CH) k[(i * HH + h) * CH + w] = val;
                else        v[(i * HH + h) * CH + (w - CH)] = val;
            } else if (col < 720) {
                qp_raw[i * 144 + (col - 576)] = val;
            } else {
                kvp_raw[i * 432 + (col - 720)] = val;
            }
        }
    }
}

// ---------------- K2: rotate+translate point projections ----------------
__global__ void k_pts_transform(const float* __restrict__ qp_raw, const float* __restrict__ kvp_raw,
                                const float* __restrict__ rot, const float* __restrict__ trans,
                                float* __restrict__ q_pts, float* __restrict__ k_pts, float* __restrict__ v_pts)
{
    int idx = blockIdx.x * blockDim.x + threadIdx.x;
    const int total = NN * HH * 16;
    if (idx >= total) return;
    int i = idx / (HH * 16);
    int r = idx % (HH * 16);
    int h = r / 16;
    int p = r % 16;

    float R[9], t3[3];
    for (int a = 0; a < 9; ++a) R[a] = rot[i * 9 + a];
    for (int a = 0; a < 3; ++a) t3[a] = trans[i * 3 + a];

    float x, y, zc;
    if (p < PQ) {
        x  = qp_raw[i * 144 + 0 * 48 + h * PQ + p];
        y  = qp_raw[i * 144 + 1 * 48 + h * PQ + p];
        zc = qp_raw[i * 144 + 2 * 48 + h * PQ + p];
    } else {
        int pp = p - PQ;
        x  = kvp_raw[i * 432 + 0 * 144 + h * 12 + pp];
        y  = kvp_raw[i * 432 + 1 * 144 + h * 12 + pp];
        zc = kvp_raw[i * 432 + 2 * 144 + h * 12 + pp];
    }
    float ox = R[0] * x + R[1] * y + R[2] * zc + t3[0];
    float oy = R[3] * x + R[4] * y + R[5] * zc + t3[1];
    float oz = R[6] * x + R[7] * y + R[8] * zc + t3[2];

    if (p < PQ) {
        int o = ((i * HH + h) * PQ + p) * 3;
        q_pts[o] = ox; q_pts[o + 1] = oy; q_pts[o + 2] = oz;
    } else {
        int pp = p - PQ;
        if (pp < PQ) {
            int o = ((i * HH + h) * PQ + pp) * 3;
            k_pts[o] = ox; k_pts[o + 1] = oy; k_pts[o + 2] = oz;
        } else {
            int o = ((i * HH + h) * PV + (pp - PQ)) * 3;
            v_pts[o] = ox; v_pts[o + 1] = oy; v_pts[o + 2] = oz;
        }
    }
}

// ---------------- K2b: bias GEMM  b_bias[h,i,j] = (z @ Wb)  via bf16 MFMA ----------------
__global__ void k_bias(const float* __restrict__ z, const float* __restrict__ Wb,
                       float* __restrict__ b_bias)
{
    int i = blockIdx.x;
    int lane = threadIdx.x & 63;
    int wave = threadIdx.x >> 6;   // 0..3
    int col  = lane & 15;
    int quad = lane >> 4;

    bf16x8 bfrag[4];
    #pragma unroll
    for (int kc = 0; kc < 4; ++kc) {
        #pragma unroll
        for (int jj = 0; jj < 8; ++jj) {
            int c = kc * 32 + quad * 8 + jj;
            float wv = (col < HH) ? Wb[c * HH + col] : 0.0f;
            bfrag[kc][jj] = (__bf16)wv;
        }
    }

    for (int tt = 0; tt < 8; ++tt) {
        int j0 = (wave + 4 * tt) * 16;
        const float* zrow = z + ((size_t)i * NN + j0 + col) * CZ;
        f32x4 acc = {0.f, 0.f, 0.f, 0.f};
        #pragma unroll
        for (int kc = 0; kc < 4; ++kc) {
            float4 z0 = *(const float4*)(zrow + kc * 32 + quad * 8);
            float4 z1 = *(const float4*)(zrow + kc * 32 + quad * 8 + 4);
            bf16x8 afrag;
            afrag[0] = (__bf16)z0.x; afrag[1] = (__bf16)z0.y;
            afrag[2] = (__bf16)z0.z; afrag[3] = (__bf16)z0.w;
            afrag[4] = (__bf16)z1.x; afrag[5] = (__bf16)z1.y;
            afrag[6] = (__bf16)z1.z; afrag[7] = (__bf16)z1.w;
            acc = __builtin_amdgcn_mfma_f32_16x16x32_bf16(afrag, bfrag[kc], acc, 0, 0, 0);
        }
        if (col < HH) {
            #pragma unroll
            for (int r = 0; r < 4; ++r) {
                int j = j0 + quad * 4 + r;
                b_bias[((size_t)col * NN + i) * NN + j] = acc[r];
            }
        }
    }
}

// ---------------- K3: attention logits (bias precomputed; no z here) ----------------
__global__ void k_logits(const float* __restrict__ b_bias, const float* __restrict__ bb,
                         const float* __restrict__ q, const float* __restrict__ k,
                         const float* __restrict__ q_pts, const float* __restrict__ k_pts,
                         const float* __restrict__ head_weights,
                         const float* __restrict__ mask,
                         float* __restrict__ logits)
{
    __shared__ float q_lds[HH * CH];
    __shared__ float qp_lds[HH * PQ * 3];
    __shared__ float hw_lds[HH];

    int i = blockIdx.y;
    int j = blockIdx.x * 256 + threadIdx.x;

    for (int t = threadIdx.x; t < HH * CH; t += 256) q_lds[t] = q[i * HH * CH + t];
    for (int t = threadIdx.x; t < HH * PQ * 3; t += 256) qp_lds[t] = q_pts[i * HH * PQ * 3 + t];
    if (threadIdx.x < HH) {
        float x = head_weights[threadIdx.x];
        hw_lds[threadIdx.x] = log1pf(expf(x)) * sqrtf(1.0f / 54.0f);
    }
    __syncthreads();

    const float qk_scale = sqrtf(1.0f / 48.0f);
    const float b_scale  = sqrtf(1.0f / 3.0f);

    float lg[HH];
    #pragma unroll
    for (int h = 0; h < HH; ++h) {
        float bias_h = b_bias[((size_t)h * NN + i) * NN + j] + bb[h];
        float acc = 0.f;
        const float* kr = k + ((size_t)j * HH + h) * CH;
        #pragma unroll
        for (int c = 0; c < CH; ++c) acc += q_lds[h * CH + c] * kr[c];
        lg[h] = acc * qk_scale + b_scale * bias_h;
    }

    #pragma unroll
    for (int h = 0; h < HH; ++h) {
        float s2 = 0.f;
        #pragma unroll
        for (int p = 0; p < PQ; ++p) {
            const float* kp = k_pts + (((size_t)j * HH + h) * PQ + p) * 3;
            float dx = qp_lds[(h * PQ + p) * 3 + 0] - kp[0];
            float dy = qp_lds[(h * PQ + p) * 3 + 1] - kp[1];
            float dz = qp_lds[(h * PQ + p) * 3 + 2] - kp[2];
            s2 += dx * dx + dy * dy + dz * dz;
        }
        lg[h] -= 0.5f * hw_lds[h] * s2;
    }

    float mi = mask[i], mj = mask[j];
    float sqm = 100000.0f * (mi * mj - 1.0f);
    #pragma unroll
    for (int h = 0; h < HH; ++h)
        logits[((size_t)h * NN + i) * NN + j] = lg[h] + sqm;
}

// ---------------- K4: row softmax ----------------
__global__ void k_softmax(float* __restrict__ logits)
{
    int row = blockIdx.x;
    float* p = logits + (size_t)row * NN;
    int t = threadIdx.x;
    float vals[8];
    float m = -1e30f;
    #pragma unroll
    for (int u = 0; u < 8; ++u) { vals[u] = p[t + u * 64]; m = fmaxf(m, vals[u]); }
    #pragma unroll
    for (int off = 32; off >= 1; off >>= 1) m = fmaxf(m, __shfl_xor(m, off));
    float ssum = 0.f;
    #pragma unroll
    for (int u = 0; u < 8; ++u) { vals[u] = expf(vals[u] - m); ssum += vals[u]; }
    #pragma unroll
    for (int off = 32; off >= 1; off >>= 1) ssum += __shfl_xor(ssum, off);
    float inv = 1.0f / ssum;
    #pragma unroll
    for (int u = 0; u < 8; ++u) p[t + u * 64] = vals[u] * inv;
}

// ---------------- K5: o = a·v and o_pt = a·v_pts (+ inverse frame, norms) ----------------
__global__ void k_out_ov(const float* __restrict__ logits, const float* __restrict__ v,
                         const float* __restrict__ v_pts,
                         const float* __restrict__ rot, const float* __restrict__ trans,
                         float* __restrict__ cat)
{
    __shared__ float a_lds[HH][NN];
    __shared__ float opt_lds[HH * PV * 3];
    int i = blockIdx.x;
    for (int h = 0; h < HH; ++h)
        for (int j = threadIdx.x; j < NN; j += 256)
            a_lds[h][j] = logits[((size_t)h * NN + i) * NN + j];
    __syncthreads();

    for (int out = threadIdx.x; out < 480; out += 256) {
        float acc = 0.f;
        if (out < 192) {
            int h = out / CH;
            for (int j = 0; j < NN; ++j)
                acc += a_lds[h][j] * v[(size_t)j * 192 + out];
            cat[(size_t)i * 2112 + out] = acc;
        } else {
            int r = out - 192;
            int h = r / (PV * 3);
            for (int j = 0; j < NN; ++j)
                acc += a_lds[h][j] * v_pts[(size_t)j * (HH * PV * 3) + r];
            opt_lds[r] = acc;
        }
    }
    __syncthreads();

    if (threadIdx.x < HH * PV) {
        int hp = threadIdx.x;
        float R[9], t3[3];
        for (int a = 0; a < 9; ++a) R[a] = rot[i * 9 + a];
        for (int a = 0; a < 3; ++a) t3[a] = trans[i * 3 + a];
        float gx = opt_lds[hp * 3 + 0] - t3[0];
        float gy = opt_lds[hp * 3 + 1] - t3[1];
        float gz = opt_lds[hp * 3 + 2] - t3[2];
        float lx = R[0] * gx + R[3] * gy + R[6] * gz;
        float ly = R[1] * gx + R[4] * gy + R[7] * gz;
        float lz = R[2] * gx + R[5] * gy + R[8] * gz;
        float* crow = cat + (size_t)i * 2112;
        crow[192 + 0 * 96 + hp] = lx;
        crow[192 + 1 * 96 + hp] = ly;
        crow[192 + 2 * 96 + hp] = lz;
        crow[480 + hp] = sqrtf(lx * lx + ly * ly + lz * lz + 1e-8f);
    }
}

// ---------------- K6: o_pair = a · z ----------------
__global__ void k_out_pair(const float* __restrict__ logits, const float* __restrict__ z,
                           float* __restrict__ cat)
{
    __shared__ float a_lds[NN][HH];
    __shared__ float part[2][CZ][HH];
    int i = blockIdx.x;
    for (int h = 0; h < HH; ++h)
        for (int j = threadIdx.x; j < NN; j += 256)
            a_lds[j][h] = logits[((size_t)h * NN + i) * NN + j];
    __syncthreads();

    int c = threadIdx.x & 127;
    int half = threadIdx.x >> 7;
    float acc[HH];
    #pragma unroll
    for (int h = 0; h < HH; ++h) acc[h] = 0.f;

    const float* zbase = z + ((size_t)i * NN) * CZ + c;
    int j0 = half * 256;
    for (int j = j0; j < j0 + 256; ++j) {
        float zv = zbase[(size_t)j * CZ];
        #pragma unroll
        for (int h = 0; h < HH; ++h) acc[h] += a_lds[j][h] * zv;
    }
    #pragma unroll
    for (int h = 0; h < HH; ++h) part[half][c][h] = acc[h];
    __syncthreads();

    if (threadIdx.x < CZ) {
        float* crow = cat + (size_t)i * 2112 + 576;
        for (int h = 0; h < HH; ++h)
            crow[h * CZ + threadIdx.x] = part[0][threadIdx.x][h] + part[1][threadIdx.x][h];
    }
}

// ---------------- K7: out = cat @ Wout + bout — tiled split-K GEMM ----------------
__global__ void k_final(const float* __restrict__ cat, const float* __restrict__ Wout,
                        const float* __restrict__ bout, float* __restrict__ out)
{
    __shared__ float As[64 * 52];
    __shared__ float Bs[48 * 64];

    int tx = threadIdx.x & 15;
    int ty = threadIdx.x >> 4;
    int n0 = blockIdx.x * 64;
    int m0 = blockIdx.y * 64;
    int k0 = blockIdx.z * 528;

    float acc[4][4];
    #pragma unroll
    for (int r = 0; r < 4; ++r)
        #pragma unroll
        for (int cc = 0; cc < 4; ++cc) acc[r][cc] = 0.f;

    for (int stage = 0; stage < 11; ++stage) {
        int kb = k0 + stage * 48;
        #pragma unroll
        for (int e = 0; e < 12; ++e) {
            int idx = e * 256 + threadIdx.x;
            int m = idx / 48, kk = idx % 48;
            As[m * 52 + kk] = cat[(size_t)(m0 + m) * 2112 + kb + kk];
        }
        #pragma unroll
        for (int e = 0; e < 12; ++e) {
            int idx = e * 256 + threadIdx.x;
            int kk = idx >> 6, n = idx & 63;
            Bs[kk * 64 + n] = Wout[(size_t)(kb + kk) * 384 + n0 + n];
        }
        __syncthreads();

        for (int kk = 0; kk < 48; kk += 4) {
            f32x4 a[4], b[4];
            #pragma unroll
            for (int r = 0; r < 4; ++r)
                a[r] = *(const f32x4*)&As[(ty * 4 + r) * 52 + kk];
            #pragma unroll
            for (int kq = 0; kq < 4; ++kq)
                b[kq] = *(const f32x4*)&Bs[(kk + kq) * 64 + tx * 4];
            #pragma unroll
            for (int kq = 0; kq < 4; ++kq)
                #pragma unroll
                for (int r = 0; r < 4; ++r)
                    #pragma unroll
                    for (int cc = 0; cc < 4; ++cc)
                        acc[r][cc] += a[r][kq] * b[kq][cc];
        }
        __syncthreads();
    }

    bool add_bias = (blockIdx.z == 0);
    #pragma unroll
    for (int r = 0; r < 4; ++r) {
        int m = m0 + ty * 4 + r;
        #pragma unroll
        for (int cc = 0; cc < 4; ++cc) {
            int n = n0 + tx * 4 + cc;
            float val = acc[r][cc] + (add_bias ? bout[n] : 0.f);
            atomicAdd(&out[(size_t)m * 384 + n], val);
        }
    }
}

extern "C" void kernel_launch(void* const* d_in, const int* in_sizes, int n_in,
                              void* d_out, int out_size, void* d_ws, size_t ws_size,
                              hipStream_t stream)
{
    const float* s     = (const float*)d_in[0];
    const float* z     = (const float*)d_in[1];
    const float* rot   = (const float*)d_in[2];
    const float* trans = (const float*)d_in[3];
    const float* mask  = (const float*)d_in[4];
    const float* Wq    = (const float*)d_in[5];
    const float* bq    = (const float*)d_in[6];
    const float* Wkv   = (const float*)d_in[7];
    const float* bkv   = (const float*)d_in[8];
    const float* Wqp   = (const float*)d_in[9];
    const float* bqp   = (const float*)d_in[10];
    const float* Wkvp  = (const float*)d_in[11];
    const float* bkvp  = (const float*)d_in[12];
    const float* Wb    = (const float*)d_in[13];
    const float* bb    = (const float*)d_in[14];
    const float* hw    = (const float*)d_in[15];
    const float* Wout  = (const float*)d_in[16];
    const float* bout  = (const float*)d_in[17];
    float* out = (float*)d_out;

    float* ws = (float*)d_ws;
    float* q       = ws;            // 98304
    float* k       = ws + 98304;    // 98304
    float* v       = ws + 196608;   // 98304
    float* qp_raw  = ws + 294912;   // 73728
    float* kvp_raw = ws + 368640;   // 221184
    float* q_pts   = ws + 589824;   // 73728
    float* k_pts   = ws + 663552;   // 73728
    float* v_pts   = ws + 737280;   // 147456
    float* logits  = ws + 884736;   // 3145728
    float* b_bias  = ws + 4030464;  // 3145728
    float* cat     = ws + 7176192;  // 1081344
    float* Wcat    = ws + 8257536;  // 442368
    float* bcat    = ws + 8699904;  // 1152    (total ~34.8 MB)

    hipMemsetAsync(out, 0, (size_t)NN * CS * sizeof(float), stream);

    hipLaunchKernelGGL(k_repack, dim3(512), dim3(256), 0, stream,
                       Wq, bq, Wkv, bkv, Wqp, bqp, Wkvp, bkvp, Wcat, bcat);
    hipLaunchKernelGGL(k_proj, dim3(18, 8), dim3(256), 0, stream,
                       s, Wcat, bcat, q, k, v, qp_raw, kvp_raw);
    hipLaunchKernelGGL(k_pts_transform, dim3(384), dim3(256), 0, stream,
                       qp_raw, kvp_raw, rot, trans, q_pts, k_pts, v_pts);
    hipLaunchKernelGGL(k_bias, dim3(NN), dim3(256), 0, stream, z, Wb, b_bias);
    hipLaunchKernelGGL(k_logits, dim3(2, NN), dim3(256), 0, stream,
                       b_bias, bb, q, k, q_pts, k_pts, hw, mask, logits);
    hipLaunchKernelGGL(k_softmax, dim3(HH * NN), dim3(64), 0, stream, logits);
    hipLaunchKernelGGL(k_out_ov, dim3(NN), dim3(256), 0, stream,
                       logits, v, v_pts, rot, trans, cat);
    hipLaunchKernelGGL(k_out_pair, dim3(NN), dim3(256), 0, stream, logits, z, cat);
    hipLaunchKernelGGL(k_final, dim3(6, 8, 4), dim3(256), 0, stream, cat, Wout, bout, out);
}